// Round 2
// baseline (3959.908 us; speedup 1.0000x reference)
//
#include <hip/hip_runtime.h>

#define NN 20000
#define EE 120000
#define BB 4
#define CH 256

typedef unsigned int uint;
typedef unsigned short ushort;

typedef __attribute__((ext_vector_type(8))) short bf16x8_t;
typedef __attribute__((ext_vector_type(4))) float f32x4;

__device__ __forceinline__ float bf2f(ushort h) {
    union { uint u; float f; } v; v.u = ((uint)h) << 16; return v.f;
}
__device__ __forceinline__ ushort f2bf(float f) {
    union { float f; uint u; } v; v.f = f;
    uint u = v.u;
    uint r = (u + 0x7fffu + ((u >> 16) & 1u)) >> 16;
    return (ushort)r;
}

// ---------------- CSR build ----------------

__global__ __launch_bounds__(256) void init_zero_kernel(int* cnt, int* fill) {
    int i = blockIdx.x * 256 + threadIdx.x;
    if (i < BB * NN) { cnt[i] = 0; fill[i] = 0; }
}

__global__ __launch_bounds__(256) void count_kernel(const int* __restrict__ edge, int* cnt) {
    int i = blockIdx.x * 256 + threadIdx.x;
    if (i >= BB * EE) return;
    int b = i / EE, e = i - b * EE;
    int dst = edge[(size_t)b * 2 * EE + EE + e];
    atomicAdd(&cnt[b * NN + dst], 1);
}

__global__ __launch_bounds__(256) void dinv_kernel(const int* __restrict__ cnt, float* dinv) {
    int i = blockIdx.x * 256 + threadIdx.x;
    if (i < BB * NN) dinv[i] = rsqrtf((float)(cnt[i] + 1));
}

__global__ __launch_bounds__(256) void scan_kernel(const int* __restrict__ cnt, int* rowptr) {
    int b = blockIdx.x;
    int t = threadIdx.x;
    int lane = t & 63, wv = t >> 6;
    __shared__ int wsum[4];
    int carry = 0;
    for (int base = 0; base < NN; base += 256) {
        int v = (base + t < NN) ? cnt[b * NN + base + t] : 0;
        int incl = v;
        #pragma unroll
        for (int off = 1; off < 64; off <<= 1) {
            int u = __shfl_up(incl, off, 64);
            if (lane >= off) incl += u;
        }
        if (lane == 63) wsum[wv] = incl;
        __syncthreads();
        int wadd = 0;
        for (int w2 = 0; w2 < wv; w2++) wadd += wsum[w2];
        int tot = wsum[0] + wsum[1] + wsum[2] + wsum[3];
        if (base + t < NN) rowptr[(size_t)b * (NN + 1) + base + t] = carry + wadd + incl - v;
        carry += tot;
        __syncthreads();
    }
    if (t == 0) rowptr[(size_t)b * (NN + 1) + NN] = carry;
}

__global__ __launch_bounds__(256) void fill_kernel(const int* __restrict__ edge,
                                                   const int* __restrict__ rowptr,
                                                   int* fill, int* colidx) {
    int i = blockIdx.x * 256 + threadIdx.x;
    if (i >= BB * EE) return;
    int b = i / EE, e = i - b * EE;
    int src = edge[(size_t)b * 2 * EE + e];
    int dst = edge[(size_t)b * 2 * EE + EE + e];
    int pos = rowptr[(size_t)b * (NN + 1) + dst] + atomicAdd(&fill[b * NN + dst], 1);
    colidx[(size_t)b * EE + pos] = src;
}

// ---------------- weight prep (float32 -> bf16) ----------------

// src float [count][256][256] (k-major), dst bf16 [count][n][k]
__global__ __launch_bounds__(256) void wt_sq_kernel(const float* __restrict__ src,
                                                    ushort* __restrict__ dst, int count) {
    int i = blockIdx.x * 256 + threadIdx.x;
    if (i >= count * 65536) return;
    int mat = i >> 16;
    int rem = i & 65535;
    int n = rem >> 8, k = rem & 255;
    dst[i] = f2bf(src[(mat << 16) + (k << 8) + n]);
}

// src float [963][256] -> dst bf16 [256][1024] (zero-padded K)
__global__ __launch_bounds__(256) void wt_lin_kernel(const float* __restrict__ src,
                                                     ushort* __restrict__ dst) {
    int i = blockIdx.x * 256 + threadIdx.x;
    if (i >= 256 * 1024) return;
    int n = i >> 10, k = i & 1023;
    dst[i] = (k < 963) ? f2bf(src[k * 256 + n]) : (ushort)0;
}

// x[b] float [20000][963] -> xp bf16 [20000][1024] zero-padded
__global__ __launch_bounds__(256) void pad_x_kernel(const float* __restrict__ x,
                                                    ushort* __restrict__ xp, int b) {
    int i = blockIdx.x * 256 + threadIdx.x;
    if (i >= NN * 1024) return;
    int row = i >> 10, k = i & 1023;
    xp[i] = (k < 963) ? f2bf(x[(size_t)b * NN * 963 + (size_t)row * 963 + k]) : (ushort)0;
}

// ---------------- MFMA GEMM: C[M][256] = A[M][K] @ Wt^T (+bias)(+relu) ----------------
// Wt stored as bf16 [256][K] (output-col major). bf16 in, fp32 acc, bf16 out.

#define BM 128
#define BN 128
#define BKT 64
#define LDK 72  // padded row stride (ushorts): only 2-way LDS bank aliasing (free, m136)

__global__ __launch_bounds__(256) void gemm_bf16(const ushort* __restrict__ A,
                                                 const ushort* __restrict__ Wt,
                                                 const float* __restrict__ bias,
                                                 ushort* __restrict__ C,
                                                 int M, int K, int relu) {
    __shared__ __align__(16) ushort As[BM * LDK];
    __shared__ __align__(16) ushort Bs[BN * LDK];
    int t = threadIdx.x;
    int lane = t & 63, wv = t >> 6;
    int m0 = blockIdx.x * BM;
    int n0 = blockIdx.y * BN;
    int lm = lane & 15, quad = lane >> 4;
    int wm = (wv >> 1) * 64, wn = (wv & 1) * 64;

    f32x4 acc[4][4];
    #pragma unroll
    for (int i = 0; i < 4; i++)
        #pragma unroll
        for (int j = 0; j < 4; j++) acc[i][j] = (f32x4){0.f, 0.f, 0.f, 0.f};

    for (int kt = 0; kt < K; kt += BKT) {
        uint4 av[4], bv[4];
        #pragma unroll
        for (int i = 0; i < 4; i++) {
            int idx = i * 256 + t;
            int row = idx >> 3, ch = idx & 7;
            int ar = m0 + row; if (ar >= M) ar = M - 1;
            av[i] = *(const uint4*)(A + (size_t)ar * K + kt + ch * 8);
            bv[i] = *(const uint4*)(Wt + (size_t)(n0 + row) * K + kt + ch * 8);
        }
        __syncthreads();
        #pragma unroll
        for (int i = 0; i < 4; i++) {
            int idx = i * 256 + t;
            int row = idx >> 3, ch = idx & 7;
            *(uint4*)(&As[row * LDK + ch * 8]) = av[i];
            *(uint4*)(&Bs[row * LDK + ch * 8]) = bv[i];
        }
        __syncthreads();
        #pragma unroll
        for (int ks = 0; ks < 2; ks++) {
            bf16x8_t af[4], bf[4];
            #pragma unroll
            for (int i = 0; i < 4; i++) {
                af[i] = *(const bf16x8_t*)(&As[(wm + i * 16 + lm) * LDK + ks * 32 + quad * 8]);
                bf[i] = *(const bf16x8_t*)(&Bs[(wn + i * 16 + lm) * LDK + ks * 32 + quad * 8]);
            }
            #pragma unroll
            for (int i = 0; i < 4; i++)
                #pragma unroll
                for (int j = 0; j < 4; j++)
                    acc[i][j] = __builtin_amdgcn_mfma_f32_16x16x32_bf16(af[i], bf[j], acc[i][j], 0, 0, 0);
        }
    }

    // epilogue: D layout col=lane&15, row=quad*4+reg
    #pragma unroll
    for (int i = 0; i < 4; i++) {
        #pragma unroll
        for (int r = 0; r < 4; r++) {
            int m = m0 + wm + i * 16 + quad * 4 + r;
            if (m < M) {
                #pragma unroll
                for (int j = 0; j < 4; j++) {
                    int n = n0 + wn + j * 16 + lm;
                    float v = acc[i][j][r];
                    if (bias) v += bias[n];
                    if (relu) v = fmaxf(v, 0.f);
                    C[(size_t)m * CH + n] = f2bf(v);
                }
            }
        }
    }
}

// ---------------- aggregation ----------------
// outv = f( sum_in norm*t1[s] + dinv^2*t1[d] + bias (+ t2[symm]) ); relu; optional
// residual (outv = (hprevf + outv)*0.5). Writes bf16 outb, and float outf if given.
// one wave per node; lane handles 4 channels.

__global__ __launch_bounds__(256) void agg_kernel(const ushort* __restrict__ t1,
                                                  const ushort* __restrict__ t2,
                                                  const int* __restrict__ symm,
                                                  const float* __restrict__ hprevf,
                                                  const float* __restrict__ bias,
                                                  const float* __restrict__ dinv,
                                                  const int* __restrict__ rowptr,
                                                  const int* __restrict__ colidx,
                                                  ushort* __restrict__ outb,
                                                  float* __restrict__ outf,
                                                  int relu) {
    int wv = threadIdx.x >> 6, lane = threadIdx.x & 63;
    int d = blockIdx.x * 4 + wv;
    int b = blockIdx.y;
    const ushort* t1b = t1 + (size_t)b * NN * CH;
    const float* dv = dinv + b * NN;
    int co = lane * 4;
    float a0 = 0.f, a1 = 0.f, a2 = 0.f, a3 = 0.f;
    int r0 = rowptr[(size_t)b * (NN + 1) + d];
    int r1 = rowptr[(size_t)b * (NN + 1) + d + 1];
    float dd = dv[d];
    const int* cb = colidx + (size_t)b * EE;
    for (int j = r0; j < r1; j++) {
        int s = cb[j];
        float w = dv[s] * dd;
        uint2 v = *(const uint2*)(t1b + (size_t)s * CH + co);
        a0 += w * bf2f((ushort)(v.x & 0xffff));
        a1 += w * bf2f((ushort)(v.x >> 16));
        a2 += w * bf2f((ushort)(v.y & 0xffff));
        a3 += w * bf2f((ushort)(v.y >> 16));
    }
    {   // self loop
        float w = dd * dd;
        uint2 v = *(const uint2*)(t1b + (size_t)d * CH + co);
        a0 += w * bf2f((ushort)(v.x & 0xffff));
        a1 += w * bf2f((ushort)(v.x >> 16));
        a2 += w * bf2f((ushort)(v.y & 0xffff));
        a3 += w * bf2f((ushort)(v.y >> 16));
    }
    float4 bi = *(const float4*)(bias + co);
    a0 += bi.x; a1 += bi.y; a2 += bi.z; a3 += bi.w;
    if (t2) {
        int sy = symm[b * NN + d];
        uint2 v = *(const uint2*)(t2 + ((size_t)b * NN + sy) * CH + co);
        a0 += bf2f((ushort)(v.x & 0xffff));
        a1 += bf2f((ushort)(v.x >> 16));
        a2 += bf2f((ushort)(v.y & 0xffff));
        a3 += bf2f((ushort)(v.y >> 16));
    }
    if (relu) {
        a0 = fmaxf(a0, 0.f); a1 = fmaxf(a1, 0.f);
        a2 = fmaxf(a2, 0.f); a3 = fmaxf(a3, 0.f);
    }
    if (hprevf) {
        float4 h = *(const float4*)(hprevf + ((size_t)b * NN + d) * CH + co);
        a0 = (h.x + a0) * 0.5f;
        a1 = (h.y + a1) * 0.5f;
        a2 = (h.z + a2) * 0.5f;
        a3 = (h.w + a3) * 0.5f;
    }
    uint2 o;
    o.x = (uint)f2bf(a0) | ((uint)f2bf(a1) << 16);
    o.y = (uint)f2bf(a2) | ((uint)f2bf(a3) << 16);
    *(uint2*)(outb + ((size_t)b * NN + d) * CH + co) = o;
    if (outf) {
        float4 of = {a0, a1, a2, a3};
        *(float4*)(outf + ((size_t)b * NN + d) * CH + co) = of;
    }
}

// ---------------- final conv (3 outputs), full fp32 ----------------

// t3[nd][c] = sum_k Hf[nd][k] * W3[k][c]; one wave per node
__global__ __launch_bounds__(256) void gemm3_kernel(const float* __restrict__ Hf,
                                                    const float* __restrict__ W3,
                                                    float* __restrict__ t3) {
    int wv = threadIdx.x >> 6, lane = threadIdx.x & 63;
    int nd = blockIdx.x * 4 + wv;  // [0, BB*NN)
    float4 hv = *(const float4*)(Hf + (size_t)nd * CH + lane * 4);
    int k0 = lane * 4;
    float s0 = 0.f, s1 = 0.f, s2 = 0.f;
    const float* hp = (const float*)&hv;
    #pragma unroll
    for (int j = 0; j < 4; j++) {
        float h = hp[j];
        s0 += h * W3[(k0 + j) * 3 + 0];
        s1 += h * W3[(k0 + j) * 3 + 1];
        s2 += h * W3[(k0 + j) * 3 + 2];
    }
    #pragma unroll
    for (int off = 32; off; off >>= 1) {
        s0 += __shfl_down(s0, off, 64);
        s1 += __shfl_down(s1, off, 64);
        s2 += __shfl_down(s2, off, 64);
    }
    if (lane == 0) {
        t3[(size_t)nd * 3 + 0] = s0;
        t3[(size_t)nd * 3 + 1] = s1;
        t3[(size_t)nd * 3 + 2] = s2;
    }
}

__global__ __launch_bounds__(256) void agg3_kernel(const float* __restrict__ t3,
                                                   const float* __restrict__ bias,
                                                   const float* __restrict__ dinv,
                                                   const int* __restrict__ rowptr,
                                                   const int* __restrict__ colidx,
                                                   float* __restrict__ out) {
    int i = blockIdx.x * 256 + threadIdx.x;
    if (i >= BB * NN) return;
    int b = i / NN, d = i - b * NN;
    const float* dv = dinv + b * NN;
    const float* t3b = t3 + (size_t)b * NN * 3;
    int r0 = rowptr[(size_t)b * (NN + 1) + d];
    int r1 = rowptr[(size_t)b * (NN + 1) + d + 1];
    float dd = dv[d];
    float a0 = 0.f, a1 = 0.f, a2 = 0.f;
    const int* cb = colidx + (size_t)b * EE;
    for (int j = r0; j < r1; j++) {
        int s = cb[j];
        float w = dv[s] * dd;
        a0 += w * t3b[s * 3 + 0];
        a1 += w * t3b[s * 3 + 1];
        a2 += w * t3b[s * 3 + 2];
    }
    float w = dd * dd;
    a0 += w * t3b[d * 3 + 0] + bias[0];
    a1 += w * t3b[d * 3 + 1] + bias[1];
    a2 += w * t3b[d * 3 + 2] + bias[2];
    size_t o = (size_t)i * 3;
    out[o + 0] = a0;
    out[o + 1] = a1;
    out[o + 2] = a2;
}

// ---------------- host ----------------

extern "C" void kernel_launch(void* const* d_in, const int* in_sizes, int n_in,
                              void* d_out, int out_size, void* d_ws, size_t ws_size,
                              hipStream_t stream) {
    const float* x     = (const float*)d_in[0];
    const int*   edge  = (const int*)d_in[1];
    const int*   symm  = (const int*)d_in[2];
    const float* linW  = (const float*)d_in[3];
    const float* linb  = (const float*)d_in[4];
    const float* c1W   = (const float*)d_in[5];
    const float* c1b   = (const float*)d_in[6];
    const float* blkW  = (const float*)d_in[7];
    const float* blkWs = (const float*)d_in[8];
    const float* blkb  = (const float*)d_in[9];
    const float* c3W   = (const float*)d_in[10];
    const float* c3b   = (const float*)d_in[11];

    char* ws = (char*)d_ws;
    size_t off = 0;
    auto alloc = [&](size_t bytes) -> void* {
        void* p = ws + off;
        off += (bytes + 255) & ~(size_t)255;
        return p;
    };
    ushort* xp     = (ushort*)alloc((size_t)NN * 1024 * 2);   // 41 MB; aliased as t1 after lin
    ushort* t1     = xp;                                      // [B*N][256] bf16
    ushort* Hb     = (ushort*)alloc((size_t)BB * NN * CH * 2);
    ushort* y      = (ushort*)alloc((size_t)BB * NN * CH * 2);
    ushort* t2     = (ushort*)alloc((size_t)BB * NN * CH * 2);
    float*  t3     = (float*) alloc((size_t)BB * NN * 3 * 4);
    ushort* linWt  = (ushort*)alloc((size_t)256 * 1024 * 2);
    ushort* c1Wt   = (ushort*)alloc((size_t)256 * 256 * 2);
    ushort* blkWt  = (ushort*)alloc((size_t)12 * 256 * 256 * 2);
    ushort* blkWst = (ushort*)alloc((size_t)12 * 256 * 256 * 2);
    int*    cnt    = (int*)  alloc((size_t)BB * NN * 4);
    int*    fill   = (int*)  alloc((size_t)BB * NN * 4);
    float*  dinv   = (float*)alloc((size_t)BB * NN * 4);
    int*    rowptr = (int*)  alloc((size_t)BB * (NN + 1) * 4);
    int*    colidx = (int*)  alloc((size_t)BB * EE * 4);

    float* Hf   = (float*)d_out;                  // [B,N,256] float (output 0 = final h)
    float* out2 = Hf + (size_t)BB * NN * CH;      // [B,N,3] float (output 1)

    // CSR + norm
    init_zero_kernel<<<(BB * NN + 255) / 256, 256, 0, stream>>>(cnt, fill);
    count_kernel<<<(BB * EE + 255) / 256, 256, 0, stream>>>(edge, cnt);
    dinv_kernel<<<(BB * NN + 255) / 256, 256, 0, stream>>>(cnt, dinv);
    scan_kernel<<<BB, 256, 0, stream>>>(cnt, rowptr);
    fill_kernel<<<(BB * EE + 255) / 256, 256, 0, stream>>>(edge, rowptr, fill, colidx);

    // weight conversion/transpose (float -> bf16)
    wt_lin_kernel<<<(256 * 1024 + 255) / 256, 256, 0, stream>>>(linW, linWt);
    wt_sq_kernel<<<(1 * 65536 + 255) / 256, 256, 0, stream>>>(c1W, c1Wt, 1);
    wt_sq_kernel<<<(12 * 65536 + 255) / 256, 256, 0, stream>>>(blkW, blkWt, 12);
    wt_sq_kernel<<<(12 * 65536 + 255) / 256, 256, 0, stream>>>(blkWs, blkWst, 12);

    // lin: per-batch pad+convert + GEMM (K=1024) -> Hb (bf16)
    for (int b = 0; b < BB; b++) {
        pad_x_kernel<<<(NN * 1024 + 255) / 256, 256, 0, stream>>>(x, xp, b);
        gemm_bf16<<<dim3((NN + BM - 1) / BM, 2), 256, 0, stream>>>(
            xp, linWt, linb, Hb + (size_t)b * NN * CH, NN, 1024, 0);
    }

    dim3 ggrid((BB * NN) / BM, 2);  // 625 x 2
    dim3 agrid(NN / 4, BB);         // 5000 x 4

    // conv1: GCN + relu -> stream h (Hb bf16 + Hf float)
    gemm_bf16<<<ggrid, 256, 0, stream>>>(Hb, c1Wt, nullptr, t1, BB * NN, 256, 0);
    agg_kernel<<<agrid, 256, 0, stream>>>(t1, nullptr, nullptr, nullptr, c1b, dinv,
                                          rowptr, colidx, Hb, Hf, 1);

    // 6 GBottleneck blocks
    for (int i = 0; i < 6; i++) {
        const ushort* W0  = blkWt  + (size_t)(2 * i) * 65536;
        const ushort* Ws0 = blkWst + (size_t)(2 * i) * 65536;
        const float*  b0  = blkb   + (size_t)(2 * i) * 256;
        const ushort* W1  = blkWt  + (size_t)(2 * i + 1) * 65536;
        const ushort* Ws1 = blkWst + (size_t)(2 * i + 1) * 65536;
        const float*  b1  = blkb   + (size_t)(2 * i + 1) * 256;

        gemm_bf16<<<ggrid, 256, 0, stream>>>(Hb, W0, nullptr, t1, BB * NN, 256, 0);
        gemm_bf16<<<ggrid, 256, 0, stream>>>(Hb, Ws0, nullptr, t2, BB * NN, 256, 0);
        agg_kernel<<<agrid, 256, 0, stream>>>(t1, t2, symm, nullptr, b0, dinv,
                                              rowptr, colidx, y, nullptr, 1);

        gemm_bf16<<<ggrid, 256, 0, stream>>>(y, W1, nullptr, t1, BB * NN, 256, 0);
        gemm_bf16<<<ggrid, 256, 0, stream>>>(y, Ws1, nullptr, t2, BB * NN, 256, 0);
        agg_kernel<<<agrid, 256, 0, stream>>>(t1, t2, symm, Hf, b1, dinv,
                                              rowptr, colidx, Hb, Hf, 1);
    }

    // conv3 in fp32 -> out2
    gemm3_kernel<<<(BB * NN) / 4, 256, 0, stream>>>(Hf, c3W, t3);
    agg3_kernel<<<(BB * NN + 255) / 256, 256, 0, stream>>>(t3, c3b, dinv,
                                                           rowptr, colidx, out2);

    (void)in_sizes; (void)n_in; (void)out_size; (void)ws_size;
}